// Round 3
// baseline (96.522 us; speedup 1.0000x reference)
//
#include <hip/hip_runtime.h>

// TreeCrfLoss fused single-dispatch:
//   pot = sum_i U[i, tl[i]]  +  sum_{c>=1} E[c, tl[(c-1)/4], tl[c]]
//   out = z - pot,  z = logsumexp(beliefs[0, 0:16])
// Thread handles nodes {2t, 2t+1}. Parent of n is (n-1)>>2.
// Last-block-done pattern: deterministic (no float atomics).

#define NTHR 256

__device__ __forceinline__ float nt_load(const float* p) {
    return __builtin_nontemporal_load(p);
}

__global__ __launch_bounds__(NTHR) void tree_crf_fused(
    const float* __restrict__ U,        // [N,16]
    const float* __restrict__ E,        // [N,16,16]
    const float* __restrict__ beliefs,  // [N,16] (row 0 only)
    const int*   __restrict__ tl,       // [N]
    float* __restrict__ out,            // [1]
    float* __restrict__ partials,       // [gridDim.x] in ws
    unsigned int* __restrict__ counter, // [1] in ws, zeroed by memset before launch
    int N)
{
    const int tid = blockIdx.x * NTHR + threadIdx.x;
    const int n0  = tid << 1;
    float acc = 0.0f;

    if (n0 + 1 < N) {
        const int n1 = n0 + 1;
        const int2 l2 = *reinterpret_cast<const int2*>(tl + n0);   // 8B aligned
        const int p1 = tl[n0 >> 2];                                 // parent label of n1
        const int p0 = (n0 >= 1) ? tl[(n0 - 1) >> 2] : 0;           // parent label of n0

        const float u0 = nt_load(&U[((size_t)n0 << 4) + l2.x]);
        const float u1 = nt_load(&U[((size_t)n1 << 4) + l2.y]);
        const float e1 = nt_load(&E[((size_t)n1 << 8) + p1 * 16 + l2.y]);
        float e0 = 0.0f;
        if (n0 >= 1)
            e0 = nt_load(&E[((size_t)n0 << 8) + p0 * 16 + l2.x]);
        acc = (u0 + u1) + (e0 + e1);
    } else if (n0 < N) {                 // single tail node (N odd)
        const int l = tl[n0];
        acc = U[((size_t)n0 << 4) + l];
        if (n0 >= 1)
            acc += E[((size_t)n0 << 8) + tl[(n0 - 1) >> 2] * 16 + l];
    }

    // wave (64-lane) + LDS block reduction
    #pragma unroll
    for (int off = 32; off > 0; off >>= 1)
        acc += __shfl_down(acc, off, 64);
    __shared__ float s[NTHR / 64];
    __shared__ int is_last;
    const int lane = threadIdx.x & 63;
    const int wave = threadIdx.x >> 6;
    if (lane == 0) s[wave] = acc;
    __syncthreads();

    if (threadIdx.x == 0) {
        float v = 0.0f;
        #pragma unroll
        for (int w = 0; w < NTHR / 64; ++w) v += s[w];
        __hip_atomic_store(&partials[blockIdx.x], v, __ATOMIC_RELAXED,
                           __HIP_MEMORY_SCOPE_AGENT);
        __threadfence();   // belt-and-braces: order partial store before counter bump
        unsigned int old = __hip_atomic_fetch_add(counter, 1u, __ATOMIC_ACQ_REL,
                                                  __HIP_MEMORY_SCOPE_AGENT);
        is_last = (old == gridDim.x - 1) ? 1 : 0;
    }
    __syncthreads();

    if (is_last) {
        // whole block sums the partials deterministically
        float a = 0.0f;
        for (unsigned int i = threadIdx.x; i < gridDim.x; i += NTHR)
            a += __hip_atomic_load(&partials[i], __ATOMIC_RELAXED,
                                   __HIP_MEMORY_SCOPE_AGENT);
        #pragma unroll
        for (int off = 32; off > 0; off >>= 1)
            a += __shfl_down(a, off, 64);
        if (lane == 0) s[wave] = a;
        __syncthreads();
        if (threadIdx.x == 0) {
            float pot = 0.0f;
            #pragma unroll
            for (int w = 0; w < NTHR / 64; ++w) pot += s[w];
            float m = beliefs[0];
            #pragma unroll
            for (int j = 1; j < 16; ++j) m = fmaxf(m, beliefs[j]);
            float se = 0.0f;
            #pragma unroll
            for (int j = 0; j < 16; ++j) se += __expf(beliefs[j] - m);
            const float z = m + __logf(se);
            out[0] = z - pot;   // -(pot - z)
        }
    }
}

extern "C" void kernel_launch(void* const* d_in, const int* in_sizes, int n_in,
                              void* d_out, int out_size, void* d_ws, size_t ws_size,
                              hipStream_t stream) {
    const float* U       = (const float*)d_in[0];
    const float* E       = (const float*)d_in[1];
    const float* beliefs = (const float*)d_in[2];
    const int*   tl      = (const int*)d_in[3];
    const int N = in_sizes[3];

    // grid: 2 nodes/thread, padded to a multiple of 256 blocks for even CU load
    int nb = (N + 2 * NTHR - 1) / (2 * NTHR);
    nb = ((nb + 255) / 256) * 256;          // 1024 for N=500000 → exactly 4 blocks/CU

    float* partials        = (float*)d_ws;              // nb floats
    unsigned int* counter  = (unsigned int*)((char*)d_ws + (size_t)nb * sizeof(float));
    float* out             = (float*)d_out;

    hipMemsetAsync(counter, 0, sizeof(unsigned int), stream);   // graph-capturable
    tree_crf_fused<<<nb, NTHR, 0, stream>>>(U, E, beliefs, tl, out,
                                            partials, counter, N);
}